// Round 6
// baseline (168.163 us; speedup 1.0000x reference)
//
#include <hip/hip_runtime.h>
#include <cstdint>

#define DIMD 1024
#define NROWS 8192
#define KDIM 2048   // 2*DIM

typedef unsigned short u16;
typedef __bf16 bf16x8 __attribute__((ext_vector_type(8)));
typedef float f32x4 __attribute__((ext_vector_type(4)));

__device__ __forceinline__ u16 f2bf(float f) {
  unsigned u = __builtin_bit_cast(unsigned, f);
  return (u16)((u + 0x7FFFu + ((u >> 16) & 1u)) >> 16);  // RNE
}

// Branch-free exact-enough GELU (A&S 7.1.26 erf, |err| <= 1.5e-7).
__device__ __forceinline__ float gelu_exact(float x) {
  float s = 0.70710678118654752f * x;
  float a = fabsf(s);
  float k = __fdividef(1.0f, fmaf(0.3275911f, a, 1.0f));
  float p = 1.061405429f;
  p = fmaf(p, k, -1.453152027f);
  p = fmaf(p, k, 1.421413741f);
  p = fmaf(p, k, -0.284496736f);
  p = fmaf(p, k, 0.254829592f);
  p = p * k;
  float e = __expf(-s * s);
  float erf_s = copysignf(fmaf(-p, e, 1.0f), s);
  return 0.5f * x * (1.0f + erf_s);
}

// ---------------------------------------------------------------------------
// Pre-kernel: conv(3x5)+bias+gelu -> x2 bf16; w2 fp32->bf16 cast. (unchanged)
// ---------------------------------------------------------------------------
__global__ __launch_bounds__(256) void pre_kernel(
    const float* __restrict__ ifeats, const float* __restrict__ tn,
    const float* __restrict__ ta, const float* __restrict__ cw,
    const float* __restrict__ cb, const float* __restrict__ w2,
    u16* __restrict__ x2, u16* __restrict__ w2b) {
  const int b = blockIdx.x;
  const int t = threadIdx.x;
  if (b < NROWS) {
    __shared__ float si[DIMD], sn[DIMD], sa[DIMD];
    ((float4*)si)[t] = ((const float4*)(ifeats + (size_t)b * DIMD))[t];
    ((float4*)sn)[t] = ((const float4*)tn)[t];
    ((float4*)sa)[t] = ((const float4*)ta)[t];
    __syncthreads();
    const int c = t >> 7;
    const int w0 = (t & 127) << 3;
    float cwn[5], cwa[5], cwi[5];
#pragma unroll
    for (int k = 0; k < 5; ++k) {
      cwn[k] = cw[c * 15 + k];
      cwa[k] = cw[c * 15 + 5 + k];
      cwi[k] = cw[c * 15 + 10 + k];
    }
    const float bias = cb[c];
    float wn[12], wa[12], wi[12];
#pragma unroll
    for (int j = 0; j < 12; ++j) {
      int wp = w0 - 2 + j;
      bool ok = (wp >= 0) && (wp < DIMD);
      wn[j] = ok ? sn[wp] : 0.f;
      wa[j] = ok ? sa[wp] : 0.f;
      wi[j] = ok ? si[wp] : 0.f;
    }
    union { u16 o[8]; uint4 u; } pk;
#pragma unroll
    for (int s = 0; s < 8; ++s) {
      float x = bias;
#pragma unroll
      for (int k = 0; k < 5; ++k) {
        x = fmaf(cwn[k], wn[s + k], x);
        x = fmaf(cwa[k], wa[s + k], x);
        x = fmaf(cwi[k], wi[s + k], x);
      }
      pk.o[s] = f2bf(gelu_exact(x));
    }
    *(uint4*)(x2 + (size_t)b * KDIM + c * DIMD + w0) = pk.u;
  } else {
    const int t2 = (b - NROWS) * 256 + t;
    const float4* p = (const float4*)(w2 + (size_t)t2 * 8);
    float4 a = p[0], bb = p[1];
    union { u16 o[8]; uint4 v; } pk;
    pk.o[0] = f2bf(a.x);  pk.o[1] = f2bf(a.y);  pk.o[2] = f2bf(a.z);  pk.o[3] = f2bf(a.w);
    pk.o[4] = f2bf(bb.x); pk.o[5] = f2bf(bb.y); pk.o[6] = f2bf(bb.z); pk.o[7] = f2bf(bb.w);
    *(uint4*)(w2b + (size_t)t2 * 8) = pk.v;
  }
}

// ---------------------------------------------------------------------------
// Producer-consumer GEMM (barrier-free K-loop).
// Waves 0-3: consumers, 64x64 quadrants of a 128x128 tile; K-loop touches
//   ONLY LDS + MFMA (no vmem) -> compiler emits fine-grained lgkmcnt, never
//   a vmcnt(0) drain (the structural stall of R2-R5, MfmaUtil pinned ~25%).
// Waves 4-7: producers; producer p stages whole BK=64 stages s=p,p+4,... via
//   32x global_load_lds(16B), waits ITS OWN vmcnt(0), then release-stores
//   flag_ready[s&1]=s+1. Buffer reuse gated by consumed[b][cw] (depth 2).
// Swizzle identical to R5's measured-0-conflict scheme.
// ---------------------------------------------------------------------------
__device__ __forceinline__ void gl_lds16(const u16* g, u16* l) {
  __builtin_amdgcn_global_load_lds(
      (__attribute__((address_space(1))) void*)g,
      (__attribute__((address_space(3))) void*)l, 16, 0, 0);
}

#define BK 64              // u16 per row per stage
#define NSTAGE (KDIM / BK) // 32

__global__ __launch_bounds__(512, 4) void gemm_bt(
    const u16* __restrict__ A,      // x2 bf16 [8192, 2048]
    const u16* __restrict__ B,      // w2 bf16 [1024, 2048]
    const float* __restrict__ ifeats,
    const float* __restrict__ b2,
    float* __restrict__ out) {
  constexpr int K = KDIM;
  __shared__ __align__(16) u16 sA[2][128 * BK];  // 16 KB each
  __shared__ __align__(16) u16 sB[2][128 * BK];
  __shared__ unsigned flag_ready[2];
  __shared__ unsigned consumed[2][4];

  const int tid = threadIdx.x;
  const int wv = tid >> 6;         // 0..7
  const int lane = tid & 63;

  // XCD-aware swizzle (FETCH 150->50 MB, kept)
  const int id = blockIdx.x;       // 0..511
  const int xcd = id & 7;
  const int s_ = id >> 3;
  const int i0 = (xcd * 8 + (s_ >> 3)) * 128;
  const int j0 = (s_ & 7) * 128;

  if (tid == 0) {
    flag_ready[0] = flag_ready[1] = 0;
#pragma unroll
    for (int b = 0; b < 2; ++b)
#pragma unroll
      for (int i = 0; i < 4; ++i) consumed[b][i] = 0;
  }
  __syncthreads();   // only barrier in the kernel (no loads outstanding)

  if (wv >= 4) {
    // ---------------- producer ----------------
    const int pid = wv - 4;
    // lane -> 16B chunk: row-within-8 = lane>>3, global chunk (lane&7)^(row&7)
    const int lrow = lane >> 3;                 // 0..7
    const int gchunk = (lane & 7) ^ lrow;       // XOR swizzle (R5-verified)
    const u16* gA = A + (size_t)(i0 + lrow) * K + gchunk * 8;
    const u16* gB = B + (size_t)(j0 + lrow) * K + gchunk * 8;
    for (int s = pid; s < NSTAGE; s += 4) {
      const int b = s & 1;
      if (s >= 2) {
        bool ok;
        do {
          ok = true;
#pragma unroll
          for (int i = 0; i < 4; ++i)
            ok &= (__atomic_load_n(&consumed[b][i], __ATOMIC_ACQUIRE) >=
                   (unsigned)(s - 1));
          if (!ok) __builtin_amdgcn_s_sleep(2);
        } while (!ok);
      }
      const size_t koff = (size_t)s * BK;
#pragma unroll
      for (int j = 0; j < 16; ++j) {            // 16 issues A + 16 issues B
        gl_lds16(gA + (size_t)j * 8 * K + koff, &sA[b][j * 512]);
        gl_lds16(gB + (size_t)j * 8 * K + koff, &sB[b][j * 512]);
      }
      __builtin_amdgcn_s_waitcnt(0);            // drain OWN loads only
      if (lane == 0)
        __atomic_store_n(&flag_ready[b], (unsigned)(s + 1), __ATOMIC_RELEASE);
    }
    return;  // producers exit; no trailing barrier needed
  }

  // ---------------- consumer ----------------
  const int wq = wv;               // quadrant 0..3
  const int wm = (wq & 1) * 64;
  const int wn = (wq >> 1) * 64;
  const int quad = lane >> 4;
  const int r16 = lane & 15;
  const int sw = r16 & 7;

  const f32x4 vzero = {0.f, 0.f, 0.f, 0.f};
  f32x4 acc[4][4];
#pragma unroll
  for (int a = 0; a < 4; ++a)
#pragma unroll
    for (int b = 0; b < 4; ++b) acc[a][b] = vzero;

  for (int s = 0; s < NSTAGE; ++s) {
    const int b = s & 1;
    while (__atomic_load_n(&flag_ready[b], __ATOMIC_ACQUIRE) < (unsigned)(s + 1))
      __builtin_amdgcn_s_sleep(1);
#pragma unroll
    for (int half = 0; half < 2; ++half) {
      const int poff = (((half * 4 + quad) ^ sw) << 3);
      bf16x8 av[4], bv[4];
#pragma unroll
      for (int mt = 0; mt < 4; ++mt)
        av[mt] = *(const bf16x8*)&sA[b][(wm + mt * 16 + r16) * BK + poff];
#pragma unroll
      for (int nt = 0; nt < 4; ++nt)
        bv[nt] = *(const bf16x8*)&sB[b][(wn + nt * 16 + r16) * BK + poff];
#pragma unroll
      for (int mt = 0; mt < 4; ++mt)
#pragma unroll
        for (int nt = 0; nt < 4; ++nt)
          acc[mt][nt] = __builtin_amdgcn_mfma_f32_16x16x32_bf16(av[mt], bv[nt], acc[mt][nt], 0, 0, 0);
    }
    // MFMA operands consumed -> frag reads complete; safe to release buffer.
    if (lane == 0)
      __atomic_store_n(&consumed[b][wq], (unsigned)(s + 1), __ATOMIC_RELEASE);
  }

  // epilogue: C/D layout col=lane&15, row=quad*4+reg
#pragma unroll
  for (int nt = 0; nt < 4; ++nt) {
    int col = j0 + wn + nt * 16 + r16;
    float bias = b2[col];
#pragma unroll
    for (int mt = 0; mt < 4; ++mt) {
      int rbase = i0 + wm + mt * 16 + quad * 4;
#pragma unroll
      for (int r = 0; r < 4; ++r) {
        size_t oix = (size_t)(rbase + r) * DIMD + col;
        out[oix] = ifeats[oix] + bias + acc[mt][nt][r];
      }
    }
  }
}

// ---------------------------------------------------------------------------
extern "C" void kernel_launch(void* const* d_in, const int* in_sizes, int n_in,
                              void* d_out, int out_size, void* d_ws, size_t ws_size,
                              hipStream_t stream) {
  const float* ifeats = (const float*)d_in[0];
  const float* tn     = (const float*)d_in[1];
  const float* ta     = (const float*)d_in[2];
  const float* cw     = (const float*)d_in[3];
  const float* cb     = (const float*)d_in[4];
  const float* w2     = (const float*)d_in[5];
  const float* b2     = (const float*)d_in[6];
  float* out = (float*)d_out;

  // ws: [0, 4MB) w2 bf16 | [4MB, 36MB) x2 bf16
  u16* w2b = (u16*)d_ws;
  u16* x2  = (u16*)((char*)d_ws + (size_t)DIMD * KDIM * 2);

  pre_kernel<<<NROWS + (DIMD * KDIM / 8) / 256, 256, 0, stream>>>(
      ifeats, tn, ta, cw, cb, w2, x2, w2b);
  gemm_bt<<<512, 512, 0, stream>>>(x2, w2b, ifeats, b2, out);
}